// Round 8
// baseline (656.882 us; speedup 1.0000x reference)
//
#include <hip/hip_runtime.h>
#include <math.h>

// Problem constants
#define B_  2
#define L_  225
#define D_  256
#define H_  4
#define DH_ 64
#define BH_ (B_*H_)
#define M_  (B_*L_)        // 450
#define LL_ (L_*L_)        // 50625
#define RHO 0.1f
#define INV_L (1.0f/225.0f)
#define INV_SQRT_D 0.125f  // 1/sqrt(64)

#define NBLK 512
#define SPIN_MAX 1000000
#define FLAG_STRIDE 16     // u32 stride between arrival flags = 64 B (no line sharing)
// bar layout (u32): [0] = release epoch | [64 + b*FLAG_STRIDE] = arrival flag of block b
#define BAR_U32S (64 + NBLK * FLAG_STRIDE)   // 8256 u32 = 33 KB

__device__ __forceinline__ float dinv_of(const float* deg, int idx) {
    return 1.0f / sqrtf(fmaxf(deg[idx], 1e-6f));
}

// Contention-free grid barrier (round-8 fix for the 85us/barrier flat counter):
//  - arrival = one atomic STORE per block to its own 64B-spaced flag (no RMW,
//    no shared-line serialization; 512 stores commit in parallel)
//  - block 0's 256 threads poll 2 flags each (one ~1us round across 32KB)
//  - release = single epoch store; spinners poll a read-only line with backoff
// Epochs 1..6 are monotonic vs the per-launch memset: no reset race, identical
// work on every graph replay. Bounded spins: failure => wrong answer, not hang.
__device__ __forceinline__ void gbar(unsigned* bar, unsigned epoch) {
    __syncthreads();
    const int b = blockIdx.x;
    const int t = threadIdx.x;
    unsigned* release = bar;
    unsigned* arrive  = bar + 64;
    if (b == 0) {
        if (t == 0) {
            __threadfence();   // device-scope release of this block's writes
            __hip_atomic_store(&arrive[0], epoch, __ATOMIC_RELEASE, __HIP_MEMORY_SCOPE_AGENT);
        }
        // every thread owns 2 flags: t*2 and t*2+1
        const int f0 = (t * 2) * FLAG_STRIDE;
        const int f1 = (t * 2 + 1) * FLAG_STRIDE;
        int spin = 0;
        for (;;) {
            unsigned a0 = __hip_atomic_load(&arrive[f0], __ATOMIC_ACQUIRE, __HIP_MEMORY_SCOPE_AGENT);
            unsigned a1 = __hip_atomic_load(&arrive[f1], __ATOMIC_ACQUIRE, __HIP_MEMORY_SCOPE_AGENT);
            if (a0 >= epoch && a1 >= epoch) break;
            __builtin_amdgcn_s_sleep(2);
            if (++spin > SPIN_MAX) break;
        }
        __syncthreads();       // all 512 arrivals confirmed
        if (t == 0) {
            __threadfence();
            __hip_atomic_store(release, epoch, __ATOMIC_RELEASE, __HIP_MEMORY_SCOPE_AGENT);
        }
        __syncthreads();
    } else {
        if (t == 0) {
            __threadfence();
            __hip_atomic_store(&arrive[b * FLAG_STRIDE], epoch, __ATOMIC_RELEASE, __HIP_MEMORY_SCOPE_AGENT);
            int spin = 0;
            while (__hip_atomic_load(release, __ATOMIC_ACQUIRE, __HIP_MEMORY_SCOPE_AGENT) < epoch) {
                __builtin_amdgcn_s_sleep(8);   // ~512 cy backoff on the read-only line
                if (++spin > SPIN_MAX) break;
            }
        }
        __syncthreads();
    }
}

struct Args {
    const float *x, *Wq, *Wk, *Wv, *Wo;
    float *out, *q, *k, *v, *S, *A, *M1, *attn, *deg, *oh;
    unsigned *bar;
};

union alignas(16) Smem {
    struct { float Xs[32][36]; float Ws[32][36]; } g;     // 9.2 KB
    struct { float Qs[32][68]; float Ks[32][68]; } sc;    // 17.4 KB (max)
    struct { float SiT[32][34]; float SkT[32][34]; } adj; // 8.7 KB
    struct { float As[32][33]; float Ss[32][34]; } m1;    // 8.6 KB
    struct { float Ms[32][33]; float Bs[32][33]; } sj;    // 8.4 KB
    struct { float P[16][226]; float rinv[16]; } sm;      // 14.5 KB
};

// ---------------------------------------------------------------------------
// Single persistent kernel: 512 blocks x 256 threads, 7 phases, 6 sw barriers.
// Phase bodies are byte-identical math to the validated round-2/7 kernels.
__global__ __launch_bounds__(256, 2) void fused_all(Args a)
{
    __shared__ Smem smem;
    const int b = blockIdx.x;
    const int t = threadIdx.x;

    // ---------------- Phase 1: q/k/v = x @ W^T  (+ deg = 1.0 init) ---------
    if (b < 360) {
        const int which = b / 120;
        const int r = b - which * 120;
        const int m0 = (r % 15) * 32, n0 = (r / 15) * 32;
        const float* W = (which == 0) ? a.Wq : (which == 1) ? a.Wk : a.Wv;
        float* out = (which == 0) ? a.q : (which == 1) ? a.k : a.v;
        const int ty = t >> 4, tx = t & 15;
        const int sr = t >> 3, sc4 = (t & 7) * 4;
        float acc[2][2] = {};
        for (int kt = 0; kt < D_; kt += 32) {
            int m = m0 + sr;
            float4 xv = (m < M_) ? *(const float4*)&a.x[m * D_ + kt + sc4]
                                 : make_float4(0.f, 0.f, 0.f, 0.f);
            float4 wv = *(const float4*)&W[(n0 + sr) * D_ + kt + sc4];
            *(float4*)&smem.g.Xs[sr][sc4] = xv;
            *(float4*)&smem.g.Ws[sr][sc4] = wv;
            __syncthreads();
            #pragma unroll
            for (int kk = 0; kk < 32; ++kk) {
                float a0 = smem.g.Xs[ty*2+0][kk], a1 = smem.g.Xs[ty*2+1][kk];
                float b0 = smem.g.Ws[tx*2+0][kk], b1 = smem.g.Ws[tx*2+1][kk];
                acc[0][0] += a0*b0; acc[0][1] += a0*b1;
                acc[1][0] += a1*b0; acc[1][1] += a1*b1;
            }
            __syncthreads();
        }
        #pragma unroll
        for (int i = 0; i < 2; ++i) {
            int m = m0 + ty*2 + i;
            if (m >= M_) continue;
            int bb = m / L_, l = m % L_;
            #pragma unroll
            for (int j = 0; j < 2; ++j) {
                int n = n0 + tx*2 + j;
                int h = n >> 6, dd = n & 63;
                out[((bb * H_ + h) * L_ + l) * DH_ + dd] = acc[i][j];
            }
        }
    } else if (b < 368) {
        int idx = (b - 360) * 256 + t;
        if (idx < BH_ * L_) a.deg[idx] = 1.0f;
    }
    gbar(a.bar, 1);

    // ---------------- Phase 2: S = q @ k^T ---------------------------------
    {
        const int bh = b >> 6, rr = b & 63;
        const int i0 = (rr >> 3) * 32, j0 = (rr & 7) * 32;
        const float* qb = a.q + bh * L_ * DH_;
        const float* kb = a.k + bh * L_ * DH_;
        #pragma unroll
        for (int s = 0; s < 2; ++s) {
            int li = t + s * 256;
            int r = li >> 4, c4 = (li & 15) * 4;
            float4 qv = (i0 + r < L_) ? *(const float4*)&qb[(i0 + r) * DH_ + c4]
                                      : make_float4(0.f,0.f,0.f,0.f);
            float4 kv = (j0 + r < L_) ? *(const float4*)&kb[(j0 + r) * DH_ + c4]
                                      : make_float4(0.f,0.f,0.f,0.f);
            *(float4*)&smem.sc.Qs[r][c4] = qv;
            *(float4*)&smem.sc.Ks[r][c4] = kv;
        }
        __syncthreads();
        const int ty = t >> 4, tx = t & 15;
        float acc[2][2] = {};
        #pragma unroll
        for (int c = 0; c < 64; ++c) {
            float a0 = smem.sc.Qs[ty*2+0][c], a1 = smem.sc.Qs[ty*2+1][c];
            float b0 = smem.sc.Ks[tx*2+0][c], b1 = smem.sc.Ks[tx*2+1][c];
            acc[0][0] += a0*b0; acc[0][1] += a0*b1;
            acc[1][0] += a1*b0; acc[1][1] += a1*b1;
        }
        float* Sb = a.S + bh * LL_;
        #pragma unroll
        for (int i = 0; i < 2; ++i) {
            int gi = i0 + ty*2 + i;
            if (gi >= L_) continue;
            #pragma unroll
            for (int j = 0; j < 2; ++j) {
                int gj = j0 + tx*2 + j;
                if (gj < L_) Sb[gi * L_ + gj] = acc[i][j];
            }
        }
    }
    gbar(a.bar, 2);

    // ---------------- Phase 3: adjacency + degree --------------------------
    {
        const int bh = b >> 6, rr = b & 63;
        const int i0 = (rr >> 3) * 32, k0 = (rr & 7) * 32;
        const float* Sb = a.S + bh * LL_;
        const int tx = t & 15, ty = t >> 4;
        float a00 = 0.f, a01 = 0.f, a10 = 0.f, a11 = 0.f;
        for (int jc = 0; jc < L_; jc += 32) {
            #pragma unroll
            for (int s = 0; s < 4; ++s) {
                int li = t + s * 256;
                int r = li >> 5, c = li & 31;
                int j = jc + c;
                smem.adj.SiT[c][r] = (i0 + r < L_ && j < L_) ? Sb[(i0 + r) * L_ + j] * 0.125f : 0.f;
                smem.adj.SkT[c][r] = (k0 + r < L_ && j < L_) ? Sb[(k0 + r) * L_ + j] * 0.125f : 0.f;
            }
            __syncthreads();
            #pragma unroll
            for (int j = 0; j < 32; ++j) {
                float2 av = *(const float2*)&smem.adj.SiT[j][ty * 2];
                float2 bv = *(const float2*)&smem.adj.SkT[j][tx * 2];
                float u;
                u = av.x * bv.x; a00 += (u > RHO) ? u : 0.f;
                u = av.x * bv.y; a01 += (u > RHO) ? u : 0.f;
                u = av.y * bv.x; a10 += (u > RHO) ? u : 0.f;
                u = av.y * bv.y; a11 += (u > RHO) ? u : 0.f;
            }
            __syncthreads();
        }
        const int gi0 = i0 + ty * 2, gk0 = k0 + tx * 2;
        float v00 = (gi0     < L_ && gk0     < L_ && gi0     != gk0    ) ? a00 * INV_L : 0.f;
        float v01 = (gi0     < L_ && gk0 + 1 < L_ && gi0     != gk0 + 1) ? a01 * INV_L : 0.f;
        float v10 = (gi0 + 1 < L_ && gk0     < L_ && gi0 + 1 != gk0    ) ? a10 * INV_L : 0.f;
        float v11 = (gi0 + 1 < L_ && gk0 + 1 < L_ && gi0 + 1 != gk0 + 1) ? a11 * INV_L : 0.f;
        float* Ab = a.A + bh * LL_;
        if (gi0 < L_) {
            if (gk0     < L_) Ab[gi0 * L_ + gk0    ] = v00;
            if (gk0 + 1 < L_) Ab[gi0 * L_ + gk0 + 1] = v01;
        }
        if (gi0 + 1 < L_) {
            if (gk0     < L_) Ab[(gi0+1) * L_ + gk0    ] = v10;
            if (gk0 + 1 < L_) Ab[(gi0+1) * L_ + gk0 + 1] = v11;
        }
        float rs0 = v00 + v01, rs1 = v10 + v11;
        #pragma unroll
        for (int m = 1; m < 16; m <<= 1) {
            rs0 += __shfl_xor(rs0, m);
            rs1 += __shfl_xor(rs1, m);
        }
        if (tx == 0) {
            if (gi0     < L_) atomicAdd(&a.deg[bh * L_ + gi0    ], rs0);
            if (gi0 + 1 < L_) atomicAdd(&a.deg[bh * L_ + gi0 + 1], rs1);
        }
    }
    gbar(a.bar, 3);

    // ---------------- Phase 4: M1 = Ahat @ S (dinv folded) -----------------
    {
        const int bh = b >> 6, rr = b & 63;
        const int i0 = (rr >> 3) * 32, c0 = (rr & 7) * 32;
        const float* Ab = a.A + bh * LL_;
        const float* Sb = a.S + bh * LL_;
        const float* db = a.deg + bh * L_;
        const int ty = t >> 4, tx = t & 15;
        float acc[2][2] = {};
        for (int jt = 0; jt < L_; jt += 32) {
            #pragma unroll
            for (int s = 0; s < 4; ++s) {
                int li = t + s * 256;
                int r = li >> 5, c = li & 31;
                int gi = i0 + r, gj = jt + c;
                float av = (gi < L_ && gj < L_) ? Ab[gi * L_ + gj] : 0.f;
                if (gi == gj && gi < L_) av += 1.f;
                smem.m1.As[r][c] = av;
                int gj2 = jt + r, gc = c0 + c;
                float sv = 0.f;
                if (gj2 < L_ && gc < L_) sv = Sb[gj2 * L_ + gc] * dinv_of(db, gj2);
                smem.m1.Ss[r][c] = sv;
            }
            __syncthreads();
            #pragma unroll
            for (int kk = 0; kk < 32; ++kk) {
                float a0 = smem.m1.As[ty*2+0][kk], a1 = smem.m1.As[ty*2+1][kk];
                float2 bv = *(const float2*)&smem.m1.Ss[kk][tx * 2];
                acc[0][0] += a0*bv.x; acc[0][1] += a0*bv.y;
                acc[1][0] += a1*bv.x; acc[1][1] += a1*bv.y;
            }
            __syncthreads();
        }
        float* Mb = a.M1 + bh * LL_;
        #pragma unroll
        for (int i = 0; i < 2; ++i) {
            int gi = i0 + ty*2 + i;
            if (gi >= L_) continue;
            float dvi = dinv_of(db, gi);
            #pragma unroll
            for (int j = 0; j < 2; ++j) {
                int gc = c0 + tx*2 + j;
                if (gc < L_) Mb[gi * L_ + gc] = acc[i][j] * dvi;
            }
        }
    }
    gbar(a.bar, 4);

    // ---------------- Phase 5: attn_logits = (M1 @ Ahat^T)/sqrt(d) ---------
    {
        const int bh = b >> 6, rr = b & 63;
        const int i0 = (rr >> 3) * 32, l0 = (rr & 7) * 32;
        const float* Mb = a.M1 + bh * LL_;
        const float* Ab = a.A + bh * LL_;
        const float* db = a.deg + bh * L_;
        const int ty = t >> 4, tx = t & 15;
        float acc[2][2] = {};
        for (int jt = 0; jt < L_; jt += 32) {
            #pragma unroll
            for (int s = 0; s < 4; ++s) {
                int li = t + s * 256;
                int r = li >> 5, c = li & 31;
                int gi = i0 + r, gj = jt + c;
                smem.sj.Ms[r][c] = (gi < L_ && gj < L_) ? Mb[gi * L_ + gj] : 0.f;
                int gl = l0 + r;
                float bv = 0.f;
                if (gl < L_ && gj < L_) {
                    bv = Ab[gl * L_ + gj];
                    if (gl == gj) bv += 1.f;
                    bv *= dinv_of(db, gj);
                }
                smem.sj.Bs[r][c] = bv;
            }
            __syncthreads();
            #pragma unroll
            for (int kk = 0; kk < 32; ++kk) {
                float a0 = smem.sj.Ms[ty*2+0][kk], a1 = smem.sj.Ms[ty*2+1][kk];
                float b0 = smem.sj.Bs[tx*2+0][kk], b1 = smem.sj.Bs[tx*2+1][kk];
                acc[0][0] += a0*b0; acc[0][1] += a0*b1;
                acc[1][0] += a1*b0; acc[1][1] += a1*b1;
            }
            __syncthreads();
        }
        float* ob = a.attn + bh * LL_;
        #pragma unroll
        for (int i = 0; i < 2; ++i) {
            int gi = i0 + ty*2 + i;
            if (gi >= L_) continue;
            #pragma unroll
            for (int j = 0; j < 2; ++j) {
                int gl = l0 + tx*2 + j;
                if (gl < L_) ob[gi * L_ + gl] = acc[i][j] * dinv_of(db, gl) * INV_SQRT_D;
            }
        }
    }
    gbar(a.bar, 5);

    // ---------------- Phase 6: softmax + attn @ V --------------------------
    if (b < 120) {
        const int bh = b / 15, i0 = (b % 15) * 16;
        const float* sb = a.attn + bh * LL_;
        const float* vb = a.v + bh * L_ * DH_;
        for (int e = t; e < 16 * L_; e += 256) {
            int r = e / L_, c = e - r * L_;
            int gi = i0 + r;
            smem.sm.P[r][c] = (gi < L_) ? sb[gi * L_ + c] : 0.f;
        }
        __syncthreads();
        {
            const int r = t >> 4, lane = t & 15;
            float m = -INFINITY;
            for (int c = lane; c < L_; c += 16) m = fmaxf(m, smem.sm.P[r][c]);
            #pragma unroll
            for (int mk = 1; mk < 16; mk <<= 1) m = fmaxf(m, __shfl_xor(m, mk));
            float ssum = 0.f;
            for (int c = lane; c < L_; c += 16) {
                float e = expf(smem.sm.P[r][c] - m);
                smem.sm.P[r][c] = e;
                ssum += e;
            }
            #pragma unroll
            for (int mk = 1; mk < 16; mk <<= 1) ssum += __shfl_xor(ssum, mk);
            if (lane == 0) smem.sm.rinv[r] = 1.0f / ssum;
        }
        __syncthreads();
        const int dd = t & 63, rg = t >> 6;
        float acc[4] = {};
        for (int l = 0; l < L_; ++l) {
            float vv = vb[l * DH_ + dd];
            #pragma unroll
            for (int u = 0; u < 4; ++u) acc[u] += smem.sm.P[rg * 4 + u][l] * vv;
        }
        const int bb = bh >> 2, h = bh & 3;
        #pragma unroll
        for (int u = 0; u < 4; ++u) {
            int r = rg * 4 + u;
            int gi = i0 + r;
            if (gi < L_) a.oh[(bb * L_ + gi) * (H_ * DH_) + h * DH_ + dd]
                             = acc[u] * smem.sm.rinv[r];
        }
    }
    gbar(a.bar, 6);

    // ---------------- Phase 7: out = oh @ Wo^T -----------------------------
    if (b < 120) {
        const int m0 = (b % 15) * 32, n0 = (b / 15) * 32;
        const int ty = t >> 4, tx = t & 15;
        const int sr = t >> 3, sc4 = (t & 7) * 4;
        float acc[2][2] = {};
        for (int kt = 0; kt < D_; kt += 32) {
            int m = m0 + sr;
            float4 xv = (m < M_) ? *(const float4*)&a.oh[m * D_ + kt + sc4]
                                 : make_float4(0.f,0.f,0.f,0.f);
            float4 wv = *(const float4*)&a.Wo[(n0 + sr) * D_ + kt + sc4];
            *(float4*)&smem.g.Xs[sr][sc4] = xv;
            *(float4*)&smem.g.Ws[sr][sc4] = wv;
            __syncthreads();
            #pragma unroll
            for (int kk = 0; kk < 32; ++kk) {
                float a0 = smem.g.Xs[ty*2+0][kk], a1 = smem.g.Xs[ty*2+1][kk];
                float b0 = smem.g.Ws[tx*2+0][kk], b1 = smem.g.Ws[tx*2+1][kk];
                acc[0][0] += a0*b0; acc[0][1] += a0*b1;
                acc[1][0] += a1*b0; acc[1][1] += a1*b1;
            }
            __syncthreads();
        }
        #pragma unroll
        for (int i = 0; i < 2; ++i) {
            int m = m0 + ty*2 + i;
            if (m >= M_) continue;
            #pragma unroll
            for (int j = 0; j < 2; ++j) {
                int n = n0 + tx*2 + j;
                a.out[m * D_ + n] = acc[i][j];
            }
        }
    }
}

// ---------------------------------------------------------------------------
extern "C" void kernel_launch(void* const* d_in, const int* in_sizes, int n_in,
                              void* d_out, int out_size, void* d_ws, size_t ws_size,
                              hipStream_t stream)
{
    const float* x  = (const float*)d_in[0];
    const float* Wq = (const float*)d_in[1];
    const float* Wk = (const float*)d_in[2];
    const float* Wv = (const float*)d_in[3];
    const float* Wo = (const float*)d_in[4];
    float* out = (float*)d_out;

    float* ws   = (float*)d_ws;
    float* q    = ws;
    float* k    = q    + B_*H_*L_*DH_;
    float* v    = k    + B_*H_*L_*DH_;
    float* S    = v    + B_*H_*L_*DH_;
    float* A    = S    + BH_*LL_;
    float* M1   = A    + BH_*LL_;
    float* attn = M1   + BH_*LL_;
    float* deg  = attn + BH_*LL_;
    float* oh   = deg  + BH_*L_;
    unsigned* bar = (unsigned*)(oh + M_*D_);   // barrier region after oh

    // Zero the barrier flags every launch (memset node is graph-capturable).
    hipMemsetAsync(bar, 0, BAR_U32S * sizeof(unsigned), stream);

    Args ha;
    ha.x = x; ha.Wq = Wq; ha.Wk = Wk; ha.Wv = Wv; ha.Wo = Wo;
    ha.out = out; ha.q = q; ha.k = k; ha.v = v; ha.S = S; ha.A = A;
    ha.M1 = M1; ha.attn = attn; ha.deg = deg; ha.oh = oh; ha.bar = bar;

    fused_all<<<dim3(NBLK), dim3(256), 0, stream>>>(ha);
}

// Round 10
// 277.622 us; speedup vs baseline: 2.3661x; 2.3661x over previous
//
#include <hip/hip_runtime.h>
#include <math.h>

// Problem constants
#define B_  2
#define L_  225
#define D_  256
#define H_  4
#define DH_ 64
#define BH_ (B_*H_)
#define M_  (B_*L_)        // 450
#define LL_ (L_*L_)        // 50625
#define RHO 0.1f
#define INV_L (1.0f/225.0f)
#define INV_SQRT_D 0.125f  // 1/sqrt(64)

#define NBLK 512
#define SPIN_MAX 20000     // worst case ~11 ms/barrier if broken: signal, not hang
#define FLAG_STRIDE 16     // u32 stride between arrival flags = 64 B (no line sharing)
// bar layout (u32): [0] = release epoch | [64 + b*FLAG_STRIDE] = arrival flag of block b
#define BAR_U32S (64 + NBLK * FLAG_STRIDE)   // 8256 u32 = 33 KB

__device__ __forceinline__ float dinv_of(const float* deg, int idx) {
    return 1.0f / sqrtf(fmaxf(deg[idx], 1e-6f));
}

// Grid barrier v4 — pure C++ builtins, minimal cache maintenance.
// Mechanism (rounds 7/8 lesson): agent-scope ACQUIRE atomic loads each emit
// buffer_inv (full XCD-L2 invalidate) -> ~80us/barrier + phase data evicted.
// Fix:
//  - polls   : __ATOMIC_RELAXED agent loads (sc0sc1 coherence-point read, NO inv)
//  - arrival : __ATOMIC_RELEASE store (waitcnt + wbl2 + store, NO inv) — makes
//              this block's phase writes globally visible before its flag
//  - gather  : block 0's 256 threads poll 2 flags each (64B-spaced, parallel)
//  - release : single RELEASE store of the epoch word
//  - acquire : exactly ONE fence(ACQUIRE, agent) per block after spin exit
//              (single buffer_inv so post-barrier cached loads can't be stale)
// Epochs 1..6 monotonic vs per-launch memset: no reset race, graph-replay safe.
// Bounded spins: any failure => deterministic wrong answer, never a hang.
__device__ __forceinline__ void gbar(unsigned* bar, unsigned epoch) {
    __syncthreads();
    const int b = blockIdx.x;
    const int t = threadIdx.x;
    unsigned* release = bar;
    unsigned* arrive  = bar + 64;
    if (b == 0) {
        if (t == 0)
            __hip_atomic_store(&arrive[0], epoch, __ATOMIC_RELEASE, __HIP_MEMORY_SCOPE_AGENT);
        const int f0 = (t * 2) * FLAG_STRIDE;
        const int f1 = (t * 2 + 1) * FLAG_STRIDE;
        int spin = 0;
        for (;;) {
            unsigned a0 = __hip_atomic_load(&arrive[f0], __ATOMIC_RELAXED, __HIP_MEMORY_SCOPE_AGENT);
            unsigned a1 = __hip_atomic_load(&arrive[f1], __ATOMIC_RELAXED, __HIP_MEMORY_SCOPE_AGENT);
            if (a0 >= epoch && a1 >= epoch) break;
            __builtin_amdgcn_s_sleep(2);
            if (++spin > SPIN_MAX) break;
        }
        __syncthreads();               // all 512 arrivals confirmed
        if (t == 0)
            __hip_atomic_store(release, epoch, __ATOMIC_RELEASE, __HIP_MEMORY_SCOPE_AGENT);
    } else {
        if (t == 0) {
            __hip_atomic_store(&arrive[b * FLAG_STRIDE], epoch, __ATOMIC_RELEASE, __HIP_MEMORY_SCOPE_AGENT);
            int spin = 0;
            while (__hip_atomic_load(release, __ATOMIC_RELAXED, __HIP_MEMORY_SCOPE_AGENT) < epoch) {
                __builtin_amdgcn_s_sleep(8);   // ~0.25us backoff on read-only line
                if (++spin > SPIN_MAX) break;
            }
        }
    }
    __syncthreads();
    if (t == 0) __builtin_amdgcn_fence(__ATOMIC_ACQUIRE, "agent");  // one buffer_inv
    __syncthreads();
}

struct Args {
    const float *x, *Wq, *Wk, *Wv, *Wo;
    float *out, *q, *k, *v, *S, *A, *M1, *attn, *deg, *oh;
    unsigned *bar;
};

union alignas(16) Smem {
    struct { float Xs[32][36]; float Ws[32][36]; } g;     // 9.2 KB
    struct { float Qs[32][68]; float Ks[32][68]; } sc;    // 17.4 KB (max)
    struct { float SiT[32][34]; float SkT[32][34]; } adj; // 8.7 KB
    struct { float As[32][33]; float Ss[32][34]; } m1;    // 8.6 KB
    struct { float Ms[32][33]; float Bs[32][33]; } sj;    // 8.4 KB
    struct { float P[16][226]; float rinv[16]; } sm;      // 14.5 KB
};

// ---------------------------------------------------------------------------
// Single persistent kernel: 512 blocks x 256 threads, 7 phases, 6 sw barriers.
// Phase bodies are byte-identical math to the validated round-2/7/8 kernels.
__global__ __launch_bounds__(256, 2) void fused_all(Args a)
{
    __shared__ Smem smem;
    const int b = blockIdx.x;
    const int t = threadIdx.x;

    // ---------------- Phase 1: q/k/v = x @ W^T  (+ deg = 1.0 init) ---------
    if (b < 360) {
        const int which = b / 120;
        const int r = b - which * 120;
        const int m0 = (r % 15) * 32, n0 = (r / 15) * 32;
        const float* W = (which == 0) ? a.Wq : (which == 1) ? a.Wk : a.Wv;
        float* out = (which == 0) ? a.q : (which == 1) ? a.k : a.v;
        const int ty = t >> 4, tx = t & 15;
        const int sr = t >> 3, sc4 = (t & 7) * 4;
        float acc[2][2] = {};
        for (int kt = 0; kt < D_; kt += 32) {
            int m = m0 + sr;
            float4 xv = (m < M_) ? *(const float4*)&a.x[m * D_ + kt + sc4]
                                 : make_float4(0.f, 0.f, 0.f, 0.f);
            float4 wv = *(const float4*)&W[(n0 + sr) * D_ + kt + sc4];
            *(float4*)&smem.g.Xs[sr][sc4] = xv;
            *(float4*)&smem.g.Ws[sr][sc4] = wv;
            __syncthreads();
            #pragma unroll
            for (int kk = 0; kk < 32; ++kk) {
                float a0 = smem.g.Xs[ty*2+0][kk], a1 = smem.g.Xs[ty*2+1][kk];
                float b0 = smem.g.Ws[tx*2+0][kk], b1 = smem.g.Ws[tx*2+1][kk];
                acc[0][0] += a0*b0; acc[0][1] += a0*b1;
                acc[1][0] += a1*b0; acc[1][1] += a1*b1;
            }
            __syncthreads();
        }
        #pragma unroll
        for (int i = 0; i < 2; ++i) {
            int m = m0 + ty*2 + i;
            if (m >= M_) continue;
            int bb = m / L_, l = m % L_;
            #pragma unroll
            for (int j = 0; j < 2; ++j) {
                int n = n0 + tx*2 + j;
                int h = n >> 6, dd = n & 63;
                out[((bb * H_ + h) * L_ + l) * DH_ + dd] = acc[i][j];
            }
        }
    } else if (b < 368) {
        int idx = (b - 360) * 256 + t;
        if (idx < BH_ * L_) a.deg[idx] = 1.0f;
    }
    gbar(a.bar, 1);

    // ---------------- Phase 2: S = q @ k^T ---------------------------------
    {
        const int bh = b >> 6, rr = b & 63;
        const int i0 = (rr >> 3) * 32, j0 = (rr & 7) * 32;
        const float* qb = a.q + bh * L_ * DH_;
        const float* kb = a.k + bh * L_ * DH_;
        #pragma unroll
        for (int s = 0; s < 2; ++s) {
            int li = t + s * 256;
            int r = li >> 4, c4 = (li & 15) * 4;
            float4 qv = (i0 + r < L_) ? *(const float4*)&qb[(i0 + r) * DH_ + c4]
                                      : make_float4(0.f,0.f,0.f,0.f);
            float4 kv = (j0 + r < L_) ? *(const float4*)&kb[(j0 + r) * DH_ + c4]
                                      : make_float4(0.f,0.f,0.f,0.f);
            *(float4*)&smem.sc.Qs[r][c4] = qv;
            *(float4*)&smem.sc.Ks[r][c4] = kv;
        }
        __syncthreads();
        const int ty = t >> 4, tx = t & 15;
        float acc[2][2] = {};
        #pragma unroll
        for (int c = 0; c < 64; ++c) {
            float a0 = smem.sc.Qs[ty*2+0][c], a1 = smem.sc.Qs[ty*2+1][c];
            float b0 = smem.sc.Ks[tx*2+0][c], b1 = smem.sc.Ks[tx*2+1][c];
            acc[0][0] += a0*b0; acc[0][1] += a0*b1;
            acc[1][0] += a1*b0; acc[1][1] += a1*b1;
        }
        float* Sb = a.S + bh * LL_;
        #pragma unroll
        for (int i = 0; i < 2; ++i) {
            int gi = i0 + ty*2 + i;
            if (gi >= L_) continue;
            #pragma unroll
            for (int j = 0; j < 2; ++j) {
                int gj = j0 + tx*2 + j;
                if (gj < L_) Sb[gi * L_ + gj] = acc[i][j];
            }
        }
    }
    gbar(a.bar, 2);

    // ---------------- Phase 3: adjacency + degree --------------------------
    {
        const int bh = b >> 6, rr = b & 63;
        const int i0 = (rr >> 3) * 32, k0 = (rr & 7) * 32;
        const float* Sb = a.S + bh * LL_;
        const int tx = t & 15, ty = t >> 4;
        float a00 = 0.f, a01 = 0.f, a10 = 0.f, a11 = 0.f;
        for (int jc = 0; jc < L_; jc += 32) {
            #pragma unroll
            for (int s = 0; s < 4; ++s) {
                int li = t + s * 256;
                int r = li >> 5, c = li & 31;
                int j = jc + c;
                smem.adj.SiT[c][r] = (i0 + r < L_ && j < L_) ? Sb[(i0 + r) * L_ + j] * 0.125f : 0.f;
                smem.adj.SkT[c][r] = (k0 + r < L_ && j < L_) ? Sb[(k0 + r) * L_ + j] * 0.125f : 0.f;
            }
            __syncthreads();
            #pragma unroll
            for (int j = 0; j < 32; ++j) {
                float2 av = *(const float2*)&smem.adj.SiT[j][ty * 2];
                float2 bv = *(const float2*)&smem.adj.SkT[j][tx * 2];
                float u;
                u = av.x * bv.x; a00 += (u > RHO) ? u : 0.f;
                u = av.x * bv.y; a01 += (u > RHO) ? u : 0.f;
                u = av.y * bv.x; a10 += (u > RHO) ? u : 0.f;
                u = av.y * bv.y; a11 += (u > RHO) ? u : 0.f;
            }
            __syncthreads();
        }
        const int gi0 = i0 + ty * 2, gk0 = k0 + tx * 2;
        float v00 = (gi0     < L_ && gk0     < L_ && gi0     != gk0    ) ? a00 * INV_L : 0.f;
        float v01 = (gi0     < L_ && gk0 + 1 < L_ && gi0     != gk0 + 1) ? a01 * INV_L : 0.f;
        float v10 = (gi0 + 1 < L_ && gk0     < L_ && gi0 + 1 != gk0    ) ? a10 * INV_L : 0.f;
        float v11 = (gi0 + 1 < L_ && gk0 + 1 < L_ && gi0 + 1 != gk0 + 1) ? a11 * INV_L : 0.f;
        float* Ab = a.A + bh * LL_;
        if (gi0 < L_) {
            if (gk0     < L_) Ab[gi0 * L_ + gk0    ] = v00;
            if (gk0 + 1 < L_) Ab[gi0 * L_ + gk0 + 1] = v01;
        }
        if (gi0 + 1 < L_) {
            if (gk0     < L_) Ab[(gi0+1) * L_ + gk0    ] = v10;
            if (gk0 + 1 < L_) Ab[(gi0+1) * L_ + gk0 + 1] = v11;
        }
        float rs0 = v00 + v01, rs1 = v10 + v11;
        #pragma unroll
        for (int m = 1; m < 16; m <<= 1) {
            rs0 += __shfl_xor(rs0, m);
            rs1 += __shfl_xor(rs1, m);
        }
        if (tx == 0) {
            if (gi0     < L_) atomicAdd(&a.deg[bh * L_ + gi0    ], rs0);
            if (gi0 + 1 < L_) atomicAdd(&a.deg[bh * L_ + gi0 + 1], rs1);
        }
    }
    gbar(a.bar, 3);

    // ---------------- Phase 4: M1 = Ahat @ S (dinv folded) -----------------
    {
        const int bh = b >> 6, rr = b & 63;
        const int i0 = (rr >> 3) * 32, c0 = (rr & 7) * 32;
        const float* Ab = a.A + bh * LL_;
        const float* Sb = a.S + bh * LL_;
        const float* db = a.deg + bh * L_;
        const int ty = t >> 4, tx = t & 15;
        float acc[2][2] = {};
        for (int jt = 0; jt < L_; jt += 32) {
            #pragma unroll
            for (int s = 0; s < 4; ++s) {
                int li = t + s * 256;
                int r = li >> 5, c = li & 31;
                int gi = i0 + r, gj = jt + c;
                float av = (gi < L_ && gj < L_) ? Ab[gi * L_ + gj] : 0.f;
                if (gi == gj && gi < L_) av += 1.f;
                smem.m1.As[r][c] = av;
                int gj2 = jt + r, gc = c0 + c;
                float sv = 0.f;
                if (gj2 < L_ && gc < L_) sv = Sb[gj2 * L_ + gc] * dinv_of(db, gj2);
                smem.m1.Ss[r][c] = sv;
            }
            __syncthreads();
            #pragma unroll
            for (int kk = 0; kk < 32; ++kk) {
                float a0 = smem.m1.As[ty*2+0][kk], a1 = smem.m1.As[ty*2+1][kk];
                float2 bv = *(const float2*)&smem.m1.Ss[kk][tx * 2];
                acc[0][0] += a0*bv.x; acc[0][1] += a0*bv.y;
                acc[1][0] += a1*bv.x; acc[1][1] += a1*bv.y;
            }
            __syncthreads();
        }
        float* Mb = a.M1 + bh * LL_;
        #pragma unroll
        for (int i = 0; i < 2; ++i) {
            int gi = i0 + ty*2 + i;
            if (gi >= L_) continue;
            float dvi = dinv_of(db, gi);
            #pragma unroll
            for (int j = 0; j < 2; ++j) {
                int gc = c0 + tx*2 + j;
                if (gc < L_) Mb[gi * L_ + gc] = acc[i][j] * dvi;
            }
        }
    }
    gbar(a.bar, 4);

    // ---------------- Phase 5: attn_logits = (M1 @ Ahat^T)/sqrt(d) ---------
    {
        const int bh = b >> 6, rr = b & 63;
        const int i0 = (rr >> 3) * 32, l0 = (rr & 7) * 32;
        const float* Mb = a.M1 + bh * LL_;
        const float* Ab = a.A + bh * LL_;
        const float* db = a.deg + bh * L_;
        const int ty = t >> 4, tx = t & 15;
        float acc[2][2] = {};
        for (int jt = 0; jt < L_; jt += 32) {
            #pragma unroll
            for (int s = 0; s < 4; ++s) {
                int li = t + s * 256;
                int r = li >> 5, c = li & 31;
                int gi = i0 + r, gj = jt + c;
                smem.sj.Ms[r][c] = (gi < L_ && gj < L_) ? Mb[gi * L_ + gj] : 0.f;
                int gl = l0 + r;
                float bv = 0.f;
                if (gl < L_ && gj < L_) {
                    bv = Ab[gl * L_ + gj];
                    if (gl == gj) bv += 1.f;
                    bv *= dinv_of(db, gj);
                }
                smem.sj.Bs[r][c] = bv;
            }
            __syncthreads();
            #pragma unroll
            for (int kk = 0; kk < 32; ++kk) {
                float a0 = smem.sj.Ms[ty*2+0][kk], a1 = smem.sj.Ms[ty*2+1][kk];
                float b0 = smem.sj.Bs[tx*2+0][kk], b1 = smem.sj.Bs[tx*2+1][kk];
                acc[0][0] += a0*b0; acc[0][1] += a0*b1;
                acc[1][0] += a1*b0; acc[1][1] += a1*b1;
            }
            __syncthreads();
        }
        float* ob = a.attn + bh * LL_;
        #pragma unroll
        for (int i = 0; i < 2; ++i) {
            int gi = i0 + ty*2 + i;
            if (gi >= L_) continue;
            #pragma unroll
            for (int j = 0; j < 2; ++j) {
                int gl = l0 + tx*2 + j;
                if (gl < L_) ob[gi * L_ + gl] = acc[i][j] * dinv_of(db, gl) * INV_SQRT_D;
            }
        }
    }
    gbar(a.bar, 5);

    // ---------------- Phase 6: softmax + attn @ V --------------------------
    if (b < 120) {
        const int bh = b / 15, i0 = (b % 15) * 16;
        const float* sb = a.attn + bh * LL_;
        const float* vb = a.v + bh * L_ * DH_;
        for (int e = t; e < 16 * L_; e += 256) {
            int r = e / L_, c = e - r * L_;
            int gi = i0 + r;
            smem.sm.P[r][c] = (gi < L_) ? sb[gi * L_ + c] : 0.f;
        }
        __syncthreads();
        {
            const int r = t >> 4, lane = t & 15;
            float m = -INFINITY;
            for (int c = lane; c < L_; c += 16) m = fmaxf(m, smem.sm.P[r][c]);
            #pragma unroll
            for (int mk = 1; mk < 16; mk <<= 1) m = fmaxf(m, __shfl_xor(m, mk));
            float ssum = 0.f;
            for (int c = lane; c < L_; c += 16) {
                float e = expf(smem.sm.P[r][c] - m);
                smem.sm.P[r][c] = e;
                ssum += e;
            }
            #pragma unroll
            for (int mk = 1; mk < 16; mk <<= 1) ssum += __shfl_xor(ssum, mk);
            if (lane == 0) smem.sm.rinv[r] = 1.0f / ssum;
        }
        __syncthreads();
        const int dd = t & 63, rg = t >> 6;
        float acc[4] = {};
        for (int l = 0; l < L_; ++l) {
            float vv = vb[l * DH_ + dd];
            #pragma unroll
            for (int u = 0; u < 4; ++u) acc[u] += smem.sm.P[rg * 4 + u][l] * vv;
        }
        const int bb = bh >> 2, h = bh & 3;
        #pragma unroll
        for (int u = 0; u < 4; ++u) {
            int r = rg * 4 + u;
            int gi = i0 + r;
            if (gi < L_) a.oh[(bb * L_ + gi) * (H_ * DH_) + h * DH_ + dd]
                             = acc[u] * smem.sm.rinv[r];
        }
    }
    gbar(a.bar, 6);

    // ---------------- Phase 7: out = oh @ Wo^T -----------------------------
    if (b < 120) {
        const int m0 = (b % 15) * 32, n0 = (b / 15) * 32;
        const int ty = t >> 4, tx = t & 15;
        const int sr = t >> 3, sc4 = (t & 7) * 4;
        float acc[2][2] = {};
        for (int kt = 0; kt < D_; kt += 32) {
            int m = m0 + sr;
            float4 xv = (m < M_) ? *(const float4*)&a.oh[m * D_ + kt + sc4]
                                 : make_float4(0.f,0.f,0.f,0.f);
            float4 wv = *(const float4*)&a.Wo[(n0 + sr) * D_ + kt + sc4];
            *(float4*)&smem.g.Xs[sr][sc4] = xv;
            *(float4*)&smem.g.Ws[sr][sc4] = wv;
            __syncthreads();
            #pragma unroll
            for (int kk = 0; kk < 32; ++kk) {
                float a0 = smem.g.Xs[ty*2+0][kk], a1 = smem.g.Xs[ty*2+1][kk];
                float b0 = smem.g.Ws[tx*2+0][kk], b1 = smem.g.Ws[tx*2+1][kk];
                acc[0][0] += a0*b0; acc[0][1] += a0*b1;
                acc[1][0] += a1*b0; acc[1][1] += a1*b1;
            }
            __syncthreads();
        }
        #pragma unroll
        for (int i = 0; i < 2; ++i) {
            int m = m0 + ty*2 + i;
            if (m >= M_) continue;
            #pragma unroll
            for (int j = 0; j < 2; ++j) {
                int n = n0 + tx*2 + j;
                a.out[m * D_ + n] = acc[i][j];
            }
        }
    }
}

// ---------------------------------------------------------------------------
extern "C" void kernel_launch(void* const* d_in, const int* in_sizes, int n_in,
                              void* d_out, int out_size, void* d_ws, size_t ws_size,
                              hipStream_t stream)
{
    const float* x  = (const float*)d_in[0];
    const float* Wq = (const float*)d_in[1];
    const float* Wk = (const float*)d_in[2];
    const float* Wv = (const float*)d_in[3];
    const float* Wo = (const float*)d_in[4];
    float* out = (float*)d_out;

    float* ws   = (float*)d_ws;
    float* q    = ws;
    float* k    = q    + B_*H_*L_*DH_;
    float* v    = k    + B_*H_*L_*DH_;
    float* S    = v    + B_*H_*L_*DH_;
    float* A    = S    + BH_*LL_;
    float* M1   = A    + BH_*LL_;
    float* attn = M1   + BH_*LL_;
    float* deg  = attn + BH_*LL_;
    float* oh   = deg  + BH_*L_;
    unsigned* bar = (unsigned*)(oh + M_*D_);   // barrier region after oh

    // Zero the barrier flags every launch (memset node is graph-capturable).
    hipMemsetAsync(bar, 0, BAR_U32S * sizeof(unsigned), stream);

    Args ha;
    ha.x = x; ha.Wq = Wq; ha.Wk = Wk; ha.Wv = Wv; ha.Wo = Wo;
    ha.out = out; ha.q = q; ha.k = k; ha.v = v; ha.S = S; ha.A = A;
    ha.M1 = M1; ha.attn = attn; ha.deg = deg; ha.oh = oh; ha.bar = bar;

    fused_all<<<dim3(NBLK), dim3(256), 0, stream>>>(ha);
}